// Round 5
// baseline (521.213 us; speedup 1.0000x reference)
//
#include <hip/hip_runtime.h>

// GCN layer: out = relu( (1/max(deg,1)) * segsum_dst(order * (hW)[src]) + b )
// h: [100000,64] f32, src/dst: [1.6M] i32, order: [1.6M] f32, W: [64,32], b: [32]
// out: [100000,32] f32
//
// Round 5 strategy: round-4 showed k_bin at 130us with 106MB WRITE_SIZE --
// every scattered 4-8B atomic/write costs a 32B memory-side transaction.
// New pipeline makes every global access coalesced except the irreducible
// hw[src] gather: LDS histograms -> exact CSR scan -> LDS-sorted partition
// (bucket-grouped coalesced copyout, payload packed in 8B) -> per-bucket
// gather with LDS f32-atomic accumulation + fused finalize.

constexpr int N_NODES = 100000;
constexpr int N_EDGES = 1600000;
constexpr int IN_F    = 64;
constexpr int OUT_F   = 32;
constexpr int SHIFT   = 7;                       // 128 nodes per bucket
constexpr int NPB     = 1 << SHIFT;              // 128
constexpr int NB      = (N_NODES + NPB - 1) >> SHIFT;  // 782 buckets
constexpr int PCHUNK  = 3125;                    // edges per k_part block (512 blocks)

// ---------------- k1: hw = h @ W, fused zero of binTot ----------------
__global__ __launch_bounds__(256) void gemm64x32_zero(const float* __restrict__ h,
                                                      const float* __restrict__ W,
                                                      float* __restrict__ hw,
                                                      int* __restrict__ binTot) {
    __shared__ float Ws[IN_F * OUT_F];   // 8 KB
    __shared__ float hs[8 * IN_F];       // 2 KB
    const int tid = threadIdx.x;

    #pragma unroll
    for (int i = tid; i < IN_F * OUT_F; i += 256) Ws[i] = W[i];

    const int rowBase = blockIdx.x * 8;          // 12500 blocks, N divisible by 8
    ((float2*)hs)[tid] = ((const float2*)(h + (size_t)rowBase * IN_F))[tid];

    // zero binTot while LDS stores land (k_count is stream-ordered after k1)
    for (int i = blockIdx.x * 256 + tid; i < NB; i += gridDim.x * 256) binTot[i] = 0;

    __syncthreads();

    const int rl = tid >> 5;   // local row 0..7
    const int f  = tid & 31;   // output feature
    float sum = 0.f;
    #pragma unroll
    for (int k = 0; k < IN_F; ++k)
        sum = fmaf(hs[rl * IN_F + k], Ws[k * OUT_F + f], sum);

    hw[(size_t)rowBase * OUT_F + tid] = sum;     // fully coalesced
}

// ---------------- k2: coarse bucket histogram (LDS-aggregated) ----------------
__global__ __launch_bounds__(256) void k_count(const int* __restrict__ dst,
                                               int* __restrict__ binTot) {
    __shared__ int hist[NB];
    const int tid = threadIdx.x;
    for (int i = tid; i < NB; i += 256) hist[i] = 0;
    __syncthreads();
    const int base = blockIdx.x * (N_EDGES / 256);   // 256 blocks x 6250 edges
    for (int j = tid; j < N_EDGES / 256; j += 256)
        atomicAdd(&hist[dst[base + j] >> SHIFT], 1);
    __syncthreads();
    for (int c = tid; c < NB; c += 256) {
        const int v = hist[c];
        if (v) atomicAdd(&binTot[c], v);
    }
}

// ---------------- k3: exclusive scan of bucket totals (1 block) ----------------
__global__ __launch_bounds__(1024) void k_scan(const int* __restrict__ binTot,
                                               int* __restrict__ binStart,
                                               int* __restrict__ cursor) {
    __shared__ int sc[1024];
    const int t = threadIdx.x;
    const int v = (t < NB) ? binTot[t] : 0;
    sc[t] = v;
    int s = v;
    for (int d = 1; d < 1024; d <<= 1) {
        __syncthreads();
        const int a = (t >= d) ? sc[t - d] : 0;
        __syncthreads();
        s += a;
        sc[t] = s;
    }
    if (t < NB) {
        const int ex = s - v;          // exclusive prefix
        binStart[t] = ex;
        cursor[t]   = ex;
    }
}

// ---------------- k4: partition edges into buckets (LDS sort, coalesced out) --
// payload: [ord f32 : 32][src : 17][dstLow : 7]  (56 bits in a u64)
__global__ __launch_bounds__(256) void k_part(const int* __restrict__ src,
                                              const int* __restrict__ dst,
                                              const float* __restrict__ ord,
                                              int* __restrict__ cursor,
                                              unsigned long long* __restrict__ coarse) {
    __shared__ unsigned long long sorted[PCHUNK];   // 25.0 KB
    __shared__ unsigned short    binOf[PCHUNK];     //  6.25 KB
    __shared__ int hist[NB];                        //  3.1 KB
    __shared__ int rnk[NB];                         //  3.1 KB
    __shared__ int gbase[NB];                       //  3.1 KB
    __shared__ int sc[1024];                        //  4.0 KB   (total ~44.7 KB)
    const int tid   = threadIdx.x;
    const int ebase = blockIdx.x * PCHUNK;          // 512 blocks x 3125 = 1.6M

    for (int i = tid; i < NB; i += 256) { hist[i] = 0; rnk[i] = 0; }
    __syncthreads();

    for (int j = tid; j < PCHUNK; j += 256)
        atomicAdd(&hist[dst[ebase + j] >> SHIFT], 1);
    __syncthreads();

    // block-local exclusive scan of hist via 1024-slot Hillis-Steele (4 slots/thread)
    #pragma unroll
    for (int j = 0; j < 4; ++j) { const int i = tid + j * 256; sc[i] = (i < NB) ? hist[i] : 0; }
    for (int d = 1; d < 1024; d <<= 1) {
        __syncthreads();
        int a[4];
        #pragma unroll
        for (int j = 0; j < 4; ++j) { const int i = tid + j * 256; a[j] = (i >= d) ? sc[i - d] : 0; }
        __syncthreads();
        #pragma unroll
        for (int j = 0; j < 4; ++j) sc[tid + j * 256] += a[j];
    }
    __syncthreads();   // sc[c] = inclusive scan; excl = sc[c] - hist[c]

    // allocate this block's span in each bucket (exact CSR, no overflow possible)
    for (int c = tid; c < NB; c += 256) {
        const int hcount = hist[c];
        if (hcount) gbase[c] = atomicAdd(&cursor[c], hcount);
    }
    __syncthreads();

    // stage bucket-sorted payloads in LDS
    for (int j = tid; j < PCHUNK; j += 256) {
        const int e  = ebase + j;
        const int d_ = dst[e];
        const int c  = d_ >> SHIFT;
        const int r  = atomicAdd(&rnk[c], 1);
        const int slot = (sc[c] - hist[c]) + r;
        const unsigned long long p =
            ((unsigned long long)__float_as_uint(ord[e]) << 32) |
            ((unsigned int)src[e] << SHIFT) | (unsigned int)(d_ & (NPB - 1));
        sorted[slot] = p;
        binOf[slot]  = (unsigned short)c;
    }
    __syncthreads();

    // coalesced copyout: consecutive slots of a bucket -> consecutive global addrs
    for (int i = tid; i < PCHUNK; i += 256) {
        const int c = binOf[i];
        coarse[(size_t)(gbase[c] + (i - (sc[c] - hist[c])))] = sorted[i];
    }
}

// ---------------- k5: per-bucket gather + LDS accumulate + finalize ----------
__global__ __launch_bounds__(256) void k_gather(const unsigned long long* __restrict__ coarse,
                                                const int* __restrict__ binStart,
                                                const int* __restrict__ binTot,
                                                const float* __restrict__ hw,
                                                const float* __restrict__ bias,
                                                float* __restrict__ out) {
    __shared__ float agg[NPB][OUT_F];   // 16 KB
    __shared__ float deg[NPB];          // 0.5 KB
    const int tid = threadIdx.x;
    const int b   = blockIdx.x;

    for (int i = tid; i < NPB * OUT_F; i += 256) ((float*)agg)[i] = 0.f;
    for (int i = tid; i < NPB; i += 256) deg[i] = 0.f;
    __syncthreads();

    const int start = binStart[b];
    const int tot   = binTot[b];
    const int g = tid >> 5;        // 8 concurrent edges per iteration
    const int f = tid & 31;        // lane f -> LDS bank f: conflict-free

    for (int e0 = 0; e0 < tot; e0 += 8) {
        const int idx = e0 + g;
        if (idx < tot) {
            const unsigned long long p = coarse[(size_t)start + idx];
            const float o  = __uint_as_float((unsigned int)(p >> 32));
            const unsigned int sd = (unsigned int)p;
            const int s  = sd >> SHIFT;          // src node (17 bits)
            const int dl = sd & (NPB - 1);       // node-in-bucket
            const float v = hw[(size_t)s * OUT_F + f];   // coalesced 128B per group
            atomicAdd(&agg[dl][f], o * v);               // ds_add_f32
            if (f == 0) atomicAdd(&deg[dl], 1.0f);
        }
    }
    __syncthreads();

    // finalize: out = relu(agg * 1/max(deg,1) + b), coalesced store
    const int nodeBase = b * NPB;
    for (int i = tid; i < NPB * OUT_F; i += 256) {
        const int node = i >> 5;
        const int ff   = i & 31;
        const int gn   = nodeBase + node;
        if (gn < N_NODES) {
            const float norm = 1.0f / fmaxf(deg[node], 1.0f);
            out[(size_t)gn * OUT_F + ff] =
                fmaxf(fmaf(agg[node][ff], norm, bias[ff]), 0.f);
        }
    }
}

extern "C" void kernel_launch(void* const* d_in, const int* in_sizes, int n_in,
                              void* d_out, int out_size, void* d_ws, size_t ws_size,
                              hipStream_t stream) {
    const float* h   = (const float*)d_in[0];
    const int*   src = (const int*)  d_in[1];
    const int*   dst = (const int*)  d_in[2];
    const float* ord = (const float*)d_in[3];
    const float* W   = (const float*)d_in[4];
    const float* b   = (const float*)d_in[5];
    float*       out = (float*)d_out;

    // ws layout (~25.6 MB):
    //   coarse  [E]   u64   12.8 MB   (8B-aligned at base)
    //   hw      [N*32] f32  12.8 MB
    //   binTot  [NB] | binStart [NB] | cursor [NB]   (~9.4 KB)
    unsigned long long* coarse = (unsigned long long*)d_ws;
    float* hw      = (float*)(coarse + N_EDGES);
    int*   binTot  = (int*)(hw + (size_t)N_NODES * OUT_F);
    int*   binStart= binTot + NB;
    int*   cursor  = binStart + NB;

    // 1) hw = h @ W, zero binTot
    hipLaunchKernelGGL(gemm64x32_zero, dim3(N_NODES / 8), dim3(256), 0, stream,
                       h, W, hw, binTot);

    // 2) coarse histogram (256 blocks x 6250 edges)
    hipLaunchKernelGGL(k_count, dim3(256), dim3(256), 0, stream, dst, binTot);

    // 3) exact CSR bases
    hipLaunchKernelGGL(k_scan, dim3(1), dim3(1024), 0, stream,
                       binTot, binStart, cursor);

    // 4) partition into buckets (512 blocks x 3125 edges)
    hipLaunchKernelGGL(k_part, dim3(N_EDGES / PCHUNK), dim3(256), 0, stream,
                       src, dst, ord, cursor, coarse);

    // 5) per-bucket gather + finalize (one block per bucket)
    hipLaunchKernelGGL(k_gather, dim3(NB), dim3(256), 0, stream,
                       coarse, binStart, binTot, hw, b, out);
}

// Round 7
// 482.752 us; speedup vs baseline: 1.0797x; 1.0797x over previous
//
#include <hip/hip_runtime.h>

// GCN layer: out = relu( (1/max(deg,1)) * segsum_dst(order * (hW)[src]) + b )
// Round 6 (resubmit; round-6 bench never acquired a GPU): round-5's k_gather
// was latency-bound at 23% occupancy (782 blocks, 1 dependent chain per
// group). Fix: NPB 128->64 (1563 gather blocks, 76% occupancy ceiling) +
// 4-deep ILP per group. k_part rebuilt with hierarchical scans at
// PCHUNK=3200 (500 blocks).

constexpr int N_NODES = 100000;
constexpr int N_EDGES = 1600000;
constexpr int IN_F    = 64;
constexpr int OUT_F   = 32;
constexpr int SHIFT   = 6;                        // 64 nodes per bucket
constexpr int NPB     = 1 << SHIFT;               // 64
constexpr int NB      = (N_NODES + NPB - 1) >> SHIFT;   // 1563
constexpr int PCHUNK  = 3200;                     // edges per k_part block
constexpr int PBLOCKS = N_EDGES / PCHUNK;         // 500
constexpr int CBLOCKS = 128;
constexpr int CE      = N_EDGES / CBLOCKS;        // 12500

// ---------------- k1: hw = h @ W, fused zero of binTot ----------------
__global__ __launch_bounds__(256) void gemm64x32_zero(const float* __restrict__ h,
                                                      const float* __restrict__ W,
                                                      float* __restrict__ hw,
                                                      int* __restrict__ binTot) {
    __shared__ float Ws[IN_F * OUT_F];   // 8 KB
    __shared__ float hs[8 * IN_F];       // 2 KB
    const int tid = threadIdx.x;

    #pragma unroll
    for (int i = tid; i < IN_F * OUT_F; i += 256) Ws[i] = W[i];

    const int rowBase = blockIdx.x * 8;          // 12500 blocks
    ((float2*)hs)[tid] = ((const float2*)(h + (size_t)rowBase * IN_F))[tid];

    for (int i = blockIdx.x * 256 + tid; i < NB; i += gridDim.x * 256) binTot[i] = 0;

    __syncthreads();

    const int rl = tid >> 5;
    const int f  = tid & 31;
    float sum = 0.f;
    #pragma unroll
    for (int k = 0; k < IN_F; ++k)
        sum = fmaf(hs[rl * IN_F + k], Ws[k * OUT_F + f], sum);

    hw[(size_t)rowBase * OUT_F + tid] = sum;
}

// ---------------- k2: bucket histogram (LDS-aggregated) ----------------
__global__ __launch_bounds__(256) void k_count(const int* __restrict__ dst,
                                               int* __restrict__ binTot) {
    __shared__ int hist[NB];
    const int tid = threadIdx.x;
    for (int i = tid; i < NB; i += 256) hist[i] = 0;
    __syncthreads();
    const int base = blockIdx.x * CE;
    for (int j = tid; j < CE; j += 256)
        atomicAdd(&hist[dst[base + j] >> SHIFT], 1);
    __syncthreads();
    for (int c = tid; c < NB; c += 256) {
        const int v = hist[c];
        if (v) atomicAdd(&binTot[c], v);
    }
}

// ---------------- k3: exclusive scan of bucket totals (1 block, 256 thr) ----
__global__ __launch_bounds__(256) void k_scan(const int* __restrict__ binTot,
                                              int* __restrict__ binStart,
                                              int* __restrict__ cursor) {
    __shared__ int wt[4];
    const int tid = threadIdx.x, lane = tid & 63, wid = tid >> 6;
    const int base = tid * 8;
    int loc[8]; int run = 0;
    #pragma unroll
    for (int j = 0; j < 8; ++j) {
        const int i = base + j;
        const int c = (i < NB) ? binTot[i] : 0;
        loc[j] = run; run += c;
    }
    int s = run;
    #pragma unroll
    for (int d = 1; d < 64; d <<= 1) { const int t = __shfl_up(s, d); if (lane >= d) s += t; }
    if (lane == 63) wt[wid] = s;
    __syncthreads();
    int wex = 0;
    for (int w = 0; w < wid; ++w) wex += wt[w];
    const int tex = wex + s - run;
    #pragma unroll
    for (int j = 0; j < 8; ++j) {
        const int i = base + j;
        if (i < NB) { const int e = tex + loc[j]; binStart[i] = e; cursor[i] = e; }
    }
}

// ---------------- k4: partition edges into buckets (LDS sort, coalesced out) --
// payload: [ord f32 : 32][src : 17+][dstLow : 6]
__global__ __launch_bounds__(256) void k_part(const int* __restrict__ src,
                                              const int* __restrict__ dst,
                                              const float* __restrict__ ord,
                                              int* __restrict__ cursor,
                                              unsigned long long* __restrict__ coarse) {
    __shared__ unsigned long long sorted[PCHUNK];   // 25.6 KB
    __shared__ unsigned short    binOf[PCHUNK];     //  6.4 KB
    __shared__ int hist[NB];                        //  6.25 KB
    __shared__ int rnk[NB];                         //  6.25 KB
    __shared__ int gbase[NB];                       //  6.25 KB
    __shared__ int sEx[NB];                         //  6.25 KB  (total ~57 KB)
    __shared__ int wt[4];
    const int tid = threadIdx.x, lane = tid & 63, wid = tid >> 6;
    const int ebase = blockIdx.x * PCHUNK;

    for (int i = tid; i < NB; i += 256) { hist[i] = 0; rnk[i] = 0; }
    __syncthreads();

    for (int j = tid; j < PCHUNK; j += 256)
        atomicAdd(&hist[dst[ebase + j] >> SHIFT], 1);
    __syncthreads();

    // hierarchical exclusive scan: hist -> sEx (8 bins/thread serial + wave shfl)
    {
        const int base = tid * 8;
        int loc[8]; int run = 0;
        #pragma unroll
        for (int j = 0; j < 8; ++j) {
            const int i = base + j;
            const int c = (i < NB) ? hist[i] : 0;
            loc[j] = run; run += c;
        }
        int s = run;
        #pragma unroll
        for (int d = 1; d < 64; d <<= 1) { const int t = __shfl_up(s, d); if (lane >= d) s += t; }
        if (lane == 63) wt[wid] = s;
        __syncthreads();
        int wex = 0;
        for (int w = 0; w < wid; ++w) wex += wt[w];
        const int tex = wex + s - run;
        #pragma unroll
        for (int j = 0; j < 8; ++j) {
            const int i = base + j;
            if (i < NB) sEx[i] = tex + loc[j];
        }
    }
    __syncthreads();

    // allocate this block's span in each bucket (exact CSR)
    for (int c = tid; c < NB; c += 256) {
        const int h = hist[c];
        if (h) gbase[c] = atomicAdd(&cursor[c], h);
    }

    // stage bucket-sorted payloads in LDS
    for (int j = tid; j < PCHUNK; j += 256) {
        const int e  = ebase + j;
        const int d_ = dst[e];
        const int c  = d_ >> SHIFT;
        const int r  = atomicAdd(&rnk[c], 1);
        const int slot = sEx[c] + r;
        sorted[slot] = ((unsigned long long)__float_as_uint(ord[e]) << 32) |
                       ((unsigned int)src[e] << SHIFT) | (unsigned int)(d_ & (NPB - 1));
        binOf[slot]  = (unsigned short)c;
    }
    __syncthreads();

    // coalesced copyout
    for (int i = tid; i < PCHUNK; i += 256) {
        const int c = binOf[i];
        coarse[(size_t)(gbase[c] + (i - sEx[c]))] = sorted[i];
    }
}

// ---------------- k5: per-bucket gather + LDS accumulate + finalize ----------
__global__ __launch_bounds__(256) void k_gather(const unsigned long long* __restrict__ coarse,
                                                const int* __restrict__ binStart,
                                                const int* __restrict__ binTot,
                                                const float* __restrict__ hw,
                                                const float* __restrict__ bias,
                                                float* __restrict__ out) {
    __shared__ float agg[NPB][OUT_F];   // 8 KB
    __shared__ float deg[NPB];          // 256 B
    const int tid = threadIdx.x;
    const int b   = blockIdx.x;

    for (int i = tid; i < NPB * OUT_F; i += 256) ((float*)agg)[i] = 0.f;
    if (tid < NPB) deg[tid] = 0.f;
    __syncthreads();

    const int start = binStart[b];
    const int tot   = binTot[b];
    const int g = tid >> 5;        // 8 groups
    const int f = tid & 31;        // lane f -> LDS bank f

    // 4-deep ILP: 32 edges in flight per block per iteration
    for (int e0 = g; e0 < tot; e0 += 32) {
        const int i1 = e0 + 8, i2 = e0 + 16, i3 = e0 + 24;
        const bool m1 = i1 < tot, m2 = i2 < tot, m3 = i3 < tot;

        unsigned long long p0 = coarse[(size_t)start + e0];
        unsigned long long p1 = 0, p2 = 0, p3 = 0;
        if (m1) p1 = coarse[(size_t)start + i1];
        if (m2) p2 = coarse[(size_t)start + i2];
        if (m3) p3 = coarse[(size_t)start + i3];

        const float o0 = __uint_as_float((unsigned)(p0 >> 32));
        const unsigned sd0 = (unsigned)p0;
        const int s0 = (int)(sd0 >> SHIFT), d0 = (int)(sd0 & (NPB - 1));
        const float v0 = hw[(size_t)s0 * OUT_F + f];

        float o1 = 0.f, v1 = 0.f; int s1_ = 0, d1 = 0;
        if (m1) { o1 = __uint_as_float((unsigned)(p1 >> 32));
                  const unsigned sd = (unsigned)p1; s1_ = (int)(sd >> SHIFT); d1 = (int)(sd & (NPB - 1));
                  v1 = hw[(size_t)s1_ * OUT_F + f]; }
        float o2 = 0.f, v2 = 0.f; int d2 = 0;
        if (m2) { o2 = __uint_as_float((unsigned)(p2 >> 32));
                  const unsigned sd = (unsigned)p2; const int s2_ = (int)(sd >> SHIFT); d2 = (int)(sd & (NPB - 1));
                  v2 = hw[(size_t)s2_ * OUT_F + f]; }
        float o3 = 0.f, v3 = 0.f; int d3 = 0;
        if (m3) { o3 = __uint_as_float((unsigned)(p3 >> 32));
                  const unsigned sd = (unsigned)p3; const int s3_ = (int)(sd >> SHIFT); d3 = (int)(sd & (NPB - 1));
                  v3 = hw[(size_t)s3_ * OUT_F + f]; }

        atomicAdd(&agg[d0][f], o0 * v0);
        if (f == 0) atomicAdd(&deg[d0], 1.0f);
        if (m1) { atomicAdd(&agg[d1][f], o1 * v1); if (f == 0) atomicAdd(&deg[d1], 1.0f); }
        if (m2) { atomicAdd(&agg[d2][f], o2 * v2); if (f == 0) atomicAdd(&deg[d2], 1.0f); }
        if (m3) { atomicAdd(&agg[d3][f], o3 * v3); if (f == 0) atomicAdd(&deg[d3], 1.0f); }
    }
    __syncthreads();

    // finalize: out = relu(agg * 1/max(deg,1) + b), coalesced store
    const int nodeBase = b * NPB;
    for (int i = tid; i < NPB * OUT_F; i += 256) {
        const int node = i >> 5;
        const int ff   = i & 31;
        const int gn   = nodeBase + node;
        if (gn < N_NODES) {
            const float norm = 1.0f / fmaxf(deg[node], 1.0f);
            out[(size_t)gn * OUT_F + ff] =
                fmaxf(fmaf(agg[node][ff], norm, bias[ff]), 0.f);
        }
    }
}

extern "C" void kernel_launch(void* const* d_in, const int* in_sizes, int n_in,
                              void* d_out, int out_size, void* d_ws, size_t ws_size,
                              hipStream_t stream) {
    const float* h   = (const float*)d_in[0];
    const int*   src = (const int*)  d_in[1];
    const int*   dst = (const int*)  d_in[2];
    const float* ord = (const float*)d_in[3];
    const float* W   = (const float*)d_in[4];
    const float* b   = (const float*)d_in[5];
    float*       out = (float*)d_out;

    // ws layout (~25.6 MB): coarse u64[E] | hw f32[N*32] | binTot | binStart | cursor
    unsigned long long* coarse = (unsigned long long*)d_ws;
    float* hw       = (float*)(coarse + N_EDGES);
    int*   binTot   = (int*)(hw + (size_t)N_NODES * OUT_F);
    int*   binStart = binTot + NB;
    int*   cursor   = binStart + NB;

    hipLaunchKernelGGL(gemm64x32_zero, dim3(N_NODES / 8), dim3(256), 0, stream,
                       h, W, hw, binTot);
    hipLaunchKernelGGL(k_count, dim3(CBLOCKS), dim3(256), 0, stream, dst, binTot);
    hipLaunchKernelGGL(k_scan, dim3(1), dim3(256), 0, stream,
                       binTot, binStart, cursor);
    hipLaunchKernelGGL(k_part, dim3(PBLOCKS), dim3(256), 0, stream,
                       src, dst, ord, cursor, coarse);
    hipLaunchKernelGGL(k_gather, dim3(NB), dim3(256), 0, stream,
                       coarse, binStart, binTot, hw, b, out);
}

// Round 8
// 474.760 us; speedup vs baseline: 1.0978x; 1.0168x over previous
//
#include <hip/hip_runtime.h>

// GCN layer: out = relu( (1/max(deg,1)) * segsum_dst(order * (hW)[src]) + b )
// Round 8: round-7 counters showed k_gather at VGPR=16 (launch_bounds(256)
// auto-capped) -> compiler serialized the 4-deep ILP; still latency-bound
// (occ 41%, VALU 6.6%). Fixes: (1) payloads staged in LDS (chain = 1 global
// load), (2) launch_bounds(256,4) + explicit unroll-8 ILP, (3) 2 blocks per
// bucket (node-split, no partial buffers) -> 3126 blocks.

constexpr int N_NODES = 100000;
constexpr int N_EDGES = 1600000;
constexpr int IN_F    = 64;
constexpr int OUT_F   = 32;
constexpr int SHIFT   = 6;                        // 64 nodes per bucket
constexpr int NPB     = 1 << SHIFT;               // 64
constexpr int NB      = (N_NODES + NPB - 1) >> SHIFT;   // 1563
constexpr int PCHUNK  = 3200;                     // edges per k_part block
constexpr int PBLOCKS = N_EDGES / PCHUNK;         // 500
constexpr int CBLOCKS = 128;
constexpr int CE      = N_EDGES / CBLOCKS;        // 12500
constexpr int CAP     = 1280;                     // payload LDS capacity (edges)

// ---------------- k1: hw = h @ W, fused zero of binTot ----------------
__global__ __launch_bounds__(256) void gemm64x32_zero(const float* __restrict__ h,
                                                      const float* __restrict__ W,
                                                      float* __restrict__ hw,
                                                      int* __restrict__ binTot) {
    __shared__ float Ws[IN_F * OUT_F];   // 8 KB
    __shared__ float hs[8 * IN_F];       // 2 KB
    const int tid = threadIdx.x;

    #pragma unroll
    for (int i = tid; i < IN_F * OUT_F; i += 256) Ws[i] = W[i];

    const int rowBase = blockIdx.x * 8;          // 12500 blocks
    ((float2*)hs)[tid] = ((const float2*)(h + (size_t)rowBase * IN_F))[tid];

    for (int i = blockIdx.x * 256 + tid; i < NB; i += gridDim.x * 256) binTot[i] = 0;

    __syncthreads();

    const int rl = tid >> 5;
    const int f  = tid & 31;
    float sum = 0.f;
    #pragma unroll
    for (int k = 0; k < IN_F; ++k)
        sum = fmaf(hs[rl * IN_F + k], Ws[k * OUT_F + f], sum);

    hw[(size_t)rowBase * OUT_F + tid] = sum;
}

// ---------------- k2: bucket histogram (LDS-aggregated) ----------------
__global__ __launch_bounds__(256) void k_count(const int* __restrict__ dst,
                                               int* __restrict__ binTot) {
    __shared__ int hist[NB];
    const int tid = threadIdx.x;
    for (int i = tid; i < NB; i += 256) hist[i] = 0;
    __syncthreads();
    const int base = blockIdx.x * CE;
    for (int j = tid; j < CE; j += 256)
        atomicAdd(&hist[dst[base + j] >> SHIFT], 1);
    __syncthreads();
    for (int c = tid; c < NB; c += 256) {
        const int v = hist[c];
        if (v) atomicAdd(&binTot[c], v);
    }
}

// ---------------- k3: exclusive scan of bucket totals (1 block, 256 thr) ----
__global__ __launch_bounds__(256) void k_scan(const int* __restrict__ binTot,
                                              int* __restrict__ binStart,
                                              int* __restrict__ cursor) {
    __shared__ int wt[4];
    const int tid = threadIdx.x, lane = tid & 63, wid = tid >> 6;
    const int base = tid * 8;
    int loc[8]; int run = 0;
    #pragma unroll
    for (int j = 0; j < 8; ++j) {
        const int i = base + j;
        const int c = (i < NB) ? binTot[i] : 0;
        loc[j] = run; run += c;
    }
    int s = run;
    #pragma unroll
    for (int d = 1; d < 64; d <<= 1) { const int t = __shfl_up(s, d); if (lane >= d) s += t; }
    if (lane == 63) wt[wid] = s;
    __syncthreads();
    int wex = 0;
    for (int w = 0; w < wid; ++w) wex += wt[w];
    const int tex = wex + s - run;
    #pragma unroll
    for (int j = 0; j < 8; ++j) {
        const int i = base + j;
        if (i < NB) { const int e = tex + loc[j]; binStart[i] = e; cursor[i] = e; }
    }
}

// ---------------- k4: partition edges into buckets (LDS sort, coalesced out) --
// payload: [ord f32 : 32][src : 17+][dstLow : 6]
__global__ __launch_bounds__(256, 2) void k_part(const int* __restrict__ src,
                                                 const int* __restrict__ dst,
                                                 const float* __restrict__ ord,
                                                 int* __restrict__ cursor,
                                                 unsigned long long* __restrict__ coarse) {
    __shared__ unsigned long long sorted[PCHUNK];   // 25.6 KB
    __shared__ unsigned short    binOf[PCHUNK];     //  6.4 KB
    __shared__ int hist[NB];                        //  6.25 KB
    __shared__ int rnk[NB];                         //  6.25 KB
    __shared__ int gbase[NB];                       //  6.25 KB
    __shared__ int sEx[NB];                         //  6.25 KB  (total ~57 KB)
    __shared__ int wt[4];
    const int tid = threadIdx.x, lane = tid & 63, wid = tid >> 6;
    const int ebase = blockIdx.x * PCHUNK;

    for (int i = tid; i < NB; i += 256) { hist[i] = 0; rnk[i] = 0; }
    __syncthreads();

    for (int j = tid; j < PCHUNK; j += 256)
        atomicAdd(&hist[dst[ebase + j] >> SHIFT], 1);
    __syncthreads();

    // hierarchical exclusive scan: hist -> sEx (8 bins/thread serial + wave shfl)
    {
        const int base = tid * 8;
        int loc[8]; int run = 0;
        #pragma unroll
        for (int j = 0; j < 8; ++j) {
            const int i = base + j;
            const int c = (i < NB) ? hist[i] : 0;
            loc[j] = run; run += c;
        }
        int s = run;
        #pragma unroll
        for (int d = 1; d < 64; d <<= 1) { const int t = __shfl_up(s, d); if (lane >= d) s += t; }
        if (lane == 63) wt[wid] = s;
        __syncthreads();
        int wex = 0;
        for (int w = 0; w < wid; ++w) wex += wt[w];
        const int tex = wex + s - run;
        #pragma unroll
        for (int j = 0; j < 8; ++j) {
            const int i = base + j;
            if (i < NB) sEx[i] = tex + loc[j];
        }
    }
    __syncthreads();

    // allocate this block's span in each bucket (exact CSR)
    for (int c = tid; c < NB; c += 256) {
        const int h = hist[c];
        if (h) gbase[c] = atomicAdd(&cursor[c], h);
    }

    // stage bucket-sorted payloads in LDS
    for (int j = tid; j < PCHUNK; j += 256) {
        const int e  = ebase + j;
        const int d_ = dst[e];
        const int c  = d_ >> SHIFT;
        const int r  = atomicAdd(&rnk[c], 1);
        const int slot = sEx[c] + r;
        sorted[slot] = ((unsigned long long)__float_as_uint(ord[e]) << 32) |
                       ((unsigned int)src[e] << SHIFT) | (unsigned int)(d_ & (NPB - 1));
        binOf[slot]  = (unsigned short)c;
    }
    __syncthreads();

    // coalesced copyout
    for (int i = tid; i < PCHUNK; i += 256) {
        const int c = binOf[i];
        coarse[(size_t)(gbase[c] + (i - sEx[c]))] = sorted[i];
    }
}

// ---------------- k5: per-half-bucket gather + LDS accumulate + finalize ----
// 2 blocks per bucket: half h owns nodes [h*32, h*32+32). Each block stages
// the bucket's payload span into LDS (coalesced), then scans it with
// explicit unroll-8 ILP, gathering hw rows only for its own nodes.
__global__ __launch_bounds__(256, 4) void k_gather(const unsigned long long* __restrict__ coarse,
                                                   const int* __restrict__ binStart,
                                                   const int* __restrict__ binTot,
                                                   const float* __restrict__ hw,
                                                   const float* __restrict__ bias,
                                                   float* __restrict__ out) {
    __shared__ unsigned long long pay[CAP];   // 10.25 KB
    __shared__ float agg[32][OUT_F];          //  4 KB
    __shared__ float deg[32];                 //  128 B
    const int tid    = threadIdx.x;
    const int bucket = blockIdx.x >> 1;
    const int half   = blockIdx.x & 1;
    const int g      = tid >> 5;     // 8 groups
    const int f      = tid & 31;     // lane f -> LDS bank f

    for (int i = tid; i < 32 * OUT_F; i += 256) ((float*)agg)[i] = 0.f;
    if (tid < 32) deg[tid] = 0.f;

    const int start = binStart[bucket];
    const int tot   = binTot[bucket];

    for (int base = 0; base < tot; base += CAP) {
        const int n = min(CAP, tot - base);
        __syncthreads();                          // pay reuse / agg-zero visibility
        for (int i = tid; i < n; i += 256)
            pay[i] = coarse[(size_t)start + base + i];
        __syncthreads();

        // scan payloads: 8 groups x unroll 8 -> stride 64
        for (int j = g; j < n; j += 64) {
            unsigned long long p[8];
            bool  mine[8];
            int   node[8];
            int   s[8];
            float o[8];
            #pragma unroll
            for (int u = 0; u < 8; ++u) {
                const int idx = j + u * 8;
                const bool val = idx < n;
                p[u] = val ? pay[idx] : 0ULL;
                const unsigned sd = (unsigned)p[u];
                const int dl = (int)(sd & (NPB - 1));
                mine[u] = val && ((dl >> 5) == half);
                node[u] = dl & 31;
                s[u]    = (int)(sd >> SHIFT);
                o[u]    = __uint_as_float((unsigned)(p[u] >> 32));
            }
            float v[8];
            #pragma unroll
            for (int u = 0; u < 8; ++u)
                if (mine[u]) v[u] = hw[(size_t)s[u] * OUT_F + f];   // 1-load chain
            #pragma unroll
            for (int u = 0; u < 8; ++u)
                if (mine[u]) {
                    atomicAdd(&agg[node[u]][f], o[u] * v[u]);
                    if (f == 0) atomicAdd(&deg[node[u]], 1.0f);
                }
        }
    }
    __syncthreads();

    // finalize this block's 32 nodes: out = relu(agg/max(deg,1) + b)
    const int nodeBase = bucket * NPB + half * 32;
    for (int i = tid; i < 32 * OUT_F; i += 256) {
        const int node = i >> 5;
        const int ff   = i & 31;
        const int gn   = nodeBase + node;
        if (gn < N_NODES) {
            const float norm = 1.0f / fmaxf(deg[node], 1.0f);
            out[(size_t)gn * OUT_F + ff] =
                fmaxf(fmaf(agg[node][ff], norm, bias[ff]), 0.f);
        }
    }
}

extern "C" void kernel_launch(void* const* d_in, const int* in_sizes, int n_in,
                              void* d_out, int out_size, void* d_ws, size_t ws_size,
                              hipStream_t stream) {
    const float* h   = (const float*)d_in[0];
    const int*   src = (const int*)  d_in[1];
    const int*   dst = (const int*)  d_in[2];
    const float* ord = (const float*)d_in[3];
    const float* W   = (const float*)d_in[4];
    const float* b   = (const float*)d_in[5];
    float*       out = (float*)d_out;

    // ws layout (~25.6 MB): coarse u64[E] | hw f32[N*32] | binTot | binStart | cursor
    unsigned long long* coarse = (unsigned long long*)d_ws;
    float* hw       = (float*)(coarse + N_EDGES);
    int*   binTot   = (int*)(hw + (size_t)N_NODES * OUT_F);
    int*   binStart = binTot + NB;
    int*   cursor   = binStart + NB;

    hipLaunchKernelGGL(gemm64x32_zero, dim3(N_NODES / 8), dim3(256), 0, stream,
                       h, W, hw, binTot);
    hipLaunchKernelGGL(k_count, dim3(CBLOCKS), dim3(256), 0, stream, dst, binTot);
    hipLaunchKernelGGL(k_scan, dim3(1), dim3(256), 0, stream,
                       binTot, binStart, cursor);
    hipLaunchKernelGGL(k_part, dim3(PBLOCKS), dim3(256), 0, stream,
                       src, dst, ord, cursor, coarse);
    hipLaunchKernelGGL(k_gather, dim3(NB * 2), dim3(256), 0, stream,
                       coarse, binStart, binTot, hw, b, out);
}